// Round 6
// baseline (564.291 us; speedup 1.0000x reference)
//
#include <hip/hip_runtime.h>
#include <cmath>

typedef unsigned int uint;

// ---- bf16 helpers (manual, RNE) ----
__device__ inline float bflo(uint u) { return __uint_as_float(u << 16); }
__device__ inline float bfhi(uint u) { return __uint_as_float(u & 0xffff0000u); }
__device__ inline uint bfpack(float a, float b) {
  uint ua = __float_as_uint(a), ub = __float_as_uint(b);
  uint ra = (ua + 0x7fffu + ((ua >> 16) & 1u)) >> 16;
  uint rb = (ub + 0x7fffu + ((ub >> 16) & 1u)) >> 16;
  return ra | (rb << 16);
}
__device__ inline ushort bf1(float a) {
  uint ua = __float_as_uint(a);
  return (ushort)((ua + 0x7fffu + ((ua >> 16) & 1u)) >> 16);
}

#define SLOT_CAP 48      // max in-degree stored; Poisson(16): P(deg>=48) ~ 1e-31
#define FILL_CHUNK 4096
#define BSHIFT 13        // 8192 nodes per bucket -> 8192*192B = 1.5MB CSR range (L2-resident)
#define MAXB 16          // >= ceil(100000/8192)=13
#define BCAP 131072      // per-bucket capacity; E/13 ~ 123K, >20 sigma headroom

// ---------------- phase A: partition edges by dst-bucket ----------------
// One pass over the edge list (nontemporal). LDS histogram -> one global
// reservation per (block,bucket) -> bucket writes are short contiguous runs.
// Bucket entry: long long, low32 = dst, high32 = src.
__global__ __launch_bounds__(256) void part_k(const int* __restrict__ src, const int* __restrict__ dst,
                                              int* __restrict__ bcnt, long long* __restrict__ buckets,
                                              int E, int nb) {
  __shared__ int lcnt[MAXB], lbase[MAXB];
  int t = threadIdx.x;
  if (t < nb) lcnt[t] = 0;
  __syncthreads();
  int base = blockIdx.x * FILL_CHUNK;
  int d[16];
  #pragma unroll
  for (int i = 0; i < 16; ++i) {
    int e = base + t + i * 256;
    d[i] = (e < E) ? __builtin_nontemporal_load(dst + e) : -1;
    if (d[i] >= 0) atomicAdd(&lcnt[d[i] >> BSHIFT], 1);
  }
  __syncthreads();
  if (t < nb) { lbase[t] = atomicAdd(&bcnt[t], lcnt[t]); lcnt[t] = 0; }
  __syncthreads();
  #pragma unroll
  for (int i = 0; i < 16; ++i) {
    if (d[i] >= 0) {
      int e = base + t + i * 256;
      int r = d[i] >> BSHIFT;
      int rank = atomicAdd(&lcnt[r], 1);
      long long s = (long long)__builtin_nontemporal_load(src + e);
      long long packed = (s << 32) | (unsigned int)d[i];
      buckets[(size_t)r * BCAP + lbase[r] + rank] = packed;
    }
  }
}

// ---------------- phase B: scatter bucket -> CSR (per-XCD 1.5MB hot region) ----
// 512 blocks; block b: xcd = b&7, bucket r = xcd + 8*(b>>8), chunk = (b>>3)&31.
// All blocks of bucket r share one XCD (blockIdx%8 round-robin heuristic), so
// the CSR range stays resident in that XCD's L2 and is written back once.
__global__ __launch_bounds__(256) void fillB_k(const long long* __restrict__ buckets, const int* __restrict__ bcnt,
                                               int* __restrict__ cursor, int* __restrict__ csr, int nb) {
  int b = blockIdx.x;
  int xcd = b & 7;
  int idx = b >> 3;
  int r = xcd + 8 * (idx >> 5);
  int chunk = idx & 31;
  if (r >= nb) return;
  int n = bcnt[r];
  int lo = chunk * 4096;
  int hi = lo + 4096; if (hi > n) hi = n;
  const long long* bk = buckets + (size_t)r * BCAP;
  for (int i = lo + threadIdx.x; i < hi; i += 256) {
    long long e = __builtin_nontemporal_load(&bk[i]);
    int d = (int)(e & 0xffffffffLL);
    int s = (int)(e >> 32);
    int pos = atomicAdd(&cursor[d], 1);
    if (pos < SLOT_CAP) csr[(size_t)d * SLOT_CAP + pos] = s;
  }
}

// dis[i] = rsqrt(true_deg + 1); cursor holds true in-degree after fill
__global__ __launch_bounds__(256) void dis_k(const int* __restrict__ cursor, float* __restrict__ dis, int n) {
  int i = blockIdx.x * 256 + threadIdx.x;
  if (i < n) dis[i] = rsqrtf((float)cursor[i] + 1.0f);
}

// graph segment boundaries (batch is sorted); gstart has G+1 entries
__global__ __launch_bounds__(256) void bounds_k(const int* __restrict__ batch, int* __restrict__ gstart,
                                                int n, int G) {
  int i = blockIdx.x * 256 + threadIdx.x;
  if (i >= n) return;
  int b = batch[i];
  int prev = (i == 0) ? -1 : batch[i - 1];
  for (int g = prev + 1; g <= b; ++g) gstart[g] = i;
  if (i == n - 1) { for (int g = b + 1; g <= G; ++g) gstart[g] = n; }
}

// ---------------- GEMM: Y[N,64](bf16) = X[N,64] @ W[64,64] ----------------

__global__ __launch_bounds__(256) void gemm_f32_k(const float* __restrict__ X, const float* __restrict__ W,
                                                  ushort* __restrict__ Y, int n) {
  __shared__ float Xs[64][64];
  int r0 = blockIdx.x * 64;
  int t = threadIdx.x;
  #pragma unroll
  for (int i = 0; i < 4; ++i) {
    int idx = t + i * 256;          // 0..1023 = 64 rows x 16 float4
    int rr = idx >> 4;
    int c4 = (idx & 15) * 4;
    int r = r0 + rr;
    float4 v = (r < n) ? ((const float4*)(X + (size_t)r * 64))[idx & 15] : make_float4(0, 0, 0, 0);
    Xs[rr][(c4 + 0 + rr) & 63] = v.x;
    Xs[rr][(c4 + 1 + rr) & 63] = v.y;
    Xs[rr][(c4 + 2 + rr) & 63] = v.z;
    Xs[rr][(c4 + 3 + rr) & 63] = v.w;
  }
  __syncthreads();
  int lane = t & 63;
  int w = t >> 6;
  float acc[16];
  #pragma unroll
  for (int c = 0; c < 16; ++c) acc[c] = 0.f;
  #pragma unroll 4
  for (int k = 0; k < 64; ++k) {
    float xv = Xs[lane][(k + lane) & 63];
    const float* wr = W + k * 64 + w * 16;   // wave-uniform -> s_load
    #pragma unroll
    for (int c = 0; c < 16; ++c) acc[c] += xv * wr[c];
  }
  int r = r0 + lane;
  if (r < n) {
    uint4* yr = (uint4*)(Y + (size_t)r * 64 + w * 16);
    yr[0] = make_uint4(bfpack(acc[0], acc[1]), bfpack(acc[2], acc[3]),
                       bfpack(acc[4], acc[5]), bfpack(acc[6], acc[7]));
    yr[1] = make_uint4(bfpack(acc[8], acc[9]), bfpack(acc[10], acc[11]),
                       bfpack(acc[12], acc[13]), bfpack(acc[14], acc[15]));
  }
}

__global__ __launch_bounds__(256) void gemm_bf16_k(const ushort* __restrict__ X, const float* __restrict__ W,
                                                   ushort* __restrict__ Y, int n) {
  __shared__ float Xs[64][64];
  int r0 = blockIdx.x * 64;
  int t = threadIdx.x;
  #pragma unroll
  for (int i = 0; i < 4; ++i) {
    int idx = t + i * 256;          // 64 rows x 16 quads of bf16
    int rr = idx >> 4;
    int c4 = (idx & 15) * 4;
    int r = r0 + rr;
    uint2 v = (r < n) ? ((const uint2*)(X + (size_t)r * 64))[idx & 15] : make_uint2(0, 0);
    Xs[rr][(c4 + 0 + rr) & 63] = bflo(v.x);
    Xs[rr][(c4 + 1 + rr) & 63] = bfhi(v.x);
    Xs[rr][(c4 + 2 + rr) & 63] = bflo(v.y);
    Xs[rr][(c4 + 3 + rr) & 63] = bfhi(v.y);
  }
  __syncthreads();
  int lane = t & 63;
  int w = t >> 6;
  float acc[16];
  #pragma unroll
  for (int c = 0; c < 16; ++c) acc[c] = 0.f;
  #pragma unroll 4
  for (int k = 0; k < 64; ++k) {
    float xv = Xs[lane][(k + lane) & 63];
    const float* wr = W + k * 64 + w * 16;
    #pragma unroll
    for (int c = 0; c < 16; ++c) acc[c] += xv * wr[c];
  }
  int r = r0 + lane;
  if (r < n) {
    uint4* yr = (uint4*)(Y + (size_t)r * 64 + w * 16);
    yr[0] = make_uint4(bfpack(acc[0], acc[1]), bfpack(acc[2], acc[3]),
                       bfpack(acc[4], acc[5]), bfpack(acc[6], acc[7]));
    yr[1] = make_uint4(bfpack(acc[8], acc[9]), bfpack(acc[10], acc[11]),
                       bfpack(acc[12], acc[13]), bfpack(acc[14], acc[15]));
  }
}

// ---------------- aggregation: one wave per node, lane = feature ----------------
// All indexing wave-uniform (node via readfirstlane) -> CSR row / degree / dis
// become s_loads; edge body ~3 VALU per edge + one 128B-coalesced row load.

__global__ __launch_bounds__(256) void agg_k(const ushort* __restrict__ Hlin,
                                             const int* __restrict__ csr,
                                             const int* __restrict__ cnt,
                                             const float* __restrict__ dis,
                                             const float* __restrict__ bias,
                                             ushort* __restrict__ Hout, int n) {
  int wv = __builtin_amdgcn_readfirstlane((int)(threadIdx.x >> 6));  // wave-uniform for LLVM
  int lane = threadIdx.x & 63;
  int node = blockIdx.x * 4 + wv;
  if (node >= n) return;
  float dn = dis[node];                        // uniform -> s_load
  float acc = bflo((uint)Hlin[(size_t)node * 64 + lane]) * (dn * dn);  // self loop
  int deg = cnt[node]; if (deg > SLOT_CAP) deg = SLOT_CAP;
  const int* row = csr + (size_t)node * SLOT_CAP;
  int e = 0;
  for (; e + 4 <= deg; e += 4) {
    int s0 = row[e + 0], s1 = row[e + 1], s2 = row[e + 2], s3 = row[e + 3];  // s_loads
    float w0 = dis[s0] * dn, w1 = dis[s1] * dn, w2 = dis[s2] * dn, w3 = dis[s3] * dn;
    float h0 = bflo((uint)Hlin[(size_t)s0 * 64 + lane]);
    float h1 = bflo((uint)Hlin[(size_t)s1 * 64 + lane]);
    float h2 = bflo((uint)Hlin[(size_t)s2 * 64 + lane]);
    float h3 = bflo((uint)Hlin[(size_t)s3 * 64 + lane]);
    acc += h0 * w0; acc += h1 * w1; acc += h2 * w2; acc += h3 * w3;
  }
  for (; e < deg; ++e) {
    int s = row[e];
    acc += bflo((uint)Hlin[(size_t)s * 64 + lane]) * (dis[s] * dn);
  }
  float v = fmaxf(acc + bias[lane], 0.f);
  Hout[(size_t)node * 64 + lane] = bf1(v);     // 128B coalesced ushort store
}

// ---------------- pooling: one block per graph, 32 rows in flight ----------------

__global__ __launch_bounds__(256) void pool_k(const ushort* __restrict__ H, const int* __restrict__ gstart,
                                              float* __restrict__ z) {
  int g = blockIdx.x;
  int t = threadIdx.x;
  int lane = t & 63, w = t >> 6;
  int slot = lane >> 3, fl = lane & 7;
  int i0 = gstart[g], i1 = gstart[g + 1];
  float s[8], m[8];
  #pragma unroll
  for (int j = 0; j < 8; ++j) { s[j] = 0.f; m[j] = 0.f; }  // max clamped at 0 (h>=0)
  for (int i = i0 + w * 8 + slot; i < i1; i += 32) {
    uint4 v = ((const uint4*)(H + (size_t)i * 64))[fl];
    float f[8] = { bflo(v.x), bfhi(v.x), bflo(v.y), bfhi(v.y),
                   bflo(v.z), bfhi(v.z), bflo(v.w), bfhi(v.w) };
    #pragma unroll
    for (int j = 0; j < 8; ++j) { s[j] += f[j]; m[j] = fmaxf(m[j], f[j]); }
  }
  #pragma unroll
  for (int msk = 8; msk <= 32; msk <<= 1) {
    #pragma unroll
    for (int j = 0; j < 8; ++j) {
      s[j] += __shfl_xor(s[j], msk, 64);
      m[j] = fmaxf(m[j], __shfl_xor(m[j], msk, 64));
    }
  }
  __shared__ float ss[4][64], sm[4][64];
  if (slot == 0) {
    #pragma unroll
    for (int j = 0; j < 8; ++j) { ss[w][fl * 8 + j] = s[j]; sm[w][fl * 8 + j] = m[j]; }
  }
  __syncthreads();
  if (t < 64) {
    float S = ss[0][t] + ss[1][t] + ss[2][t] + ss[3][t];
    float M = fmaxf(fmaxf(sm[0][t], sm[1][t]), fmaxf(sm[2][t], sm[3][t]));
    float cnt = (float)(i1 - i0);
    float mean = (cnt > 0.f) ? S / cnt : 0.f;
    z[g * 192 + t]       += mean;
    z[g * 192 + 64 + t]  += M;
    z[g * 192 + 128 + t] += S;
  }
}

// ---------------- MLP head + log_softmax ----------------
__global__ __launch_bounds__(64) void mlp_k(const float* __restrict__ z,
                                            const float* __restrict__ fc1w, const float* __restrict__ fc1b,
                                            const float* __restrict__ fc2w, const float* __restrict__ fc2b,
                                            const float* __restrict__ fc3w, const float* __restrict__ fc3b,
                                            float* __restrict__ out) {
  int g = blockIdx.x; int t = threadIdx.x;
  __shared__ float zr[192], a1[64], a2[32], a3[10];
  for (int i = t; i < 192; i += 64) zr[i] = z[g * 192 + i];
  __syncthreads();
  float acc = fc1b[t];
  for (int k = 0; k < 192; ++k) acc += zr[k] * fc1w[k * 64 + t];
  a1[t] = fmaxf(acc, 0.f);
  __syncthreads();
  if (t < 32) {
    float a = fc2b[t];
    #pragma unroll
    for (int k = 0; k < 64; ++k) a += a1[k] * fc2w[k * 32 + t];
    a2[t] = fmaxf(a, 0.f);
  }
  __syncthreads();
  if (t < 10) {
    float a = fc3b[t];
    #pragma unroll
    for (int k = 0; k < 32; ++k) a += a2[k] * fc3w[k * 10 + t];
    a3[t] = a;
  }
  __syncthreads();
  if (t == 0) {
    float mx = a3[0];
    for (int i = 1; i < 10; ++i) mx = fmaxf(mx, a3[i]);
    float sum = 0.f;
    for (int i = 0; i < 10; ++i) sum += expf(a3[i] - mx);
    float lse = mx + logf(sum);
    for (int i = 0; i < 10; ++i) out[g * 10 + i] = a3[i] - lse;
  }
}

extern "C" void kernel_launch(void* const* d_in, const int* in_sizes, int n_in,
                              void* d_out, int out_size, void* d_ws, size_t ws_size,
                              hipStream_t stream) {
  const float* x    = (const float*)d_in[0];
  const int*   ei   = (const int*)  d_in[1];
  const int*   batch= (const int*)  d_in[2];
  const float* W1   = (const float*)d_in[3];
  const float* b1   = (const float*)d_in[4];
  const float* W2   = (const float*)d_in[5];
  const float* b2   = (const float*)d_in[6];
  const float* W3   = (const float*)d_in[7];
  const float* b3   = (const float*)d_in[8];
  const float* fc1w = (const float*)d_in[9];
  const float* fc1b = (const float*)d_in[10];
  const float* fc2w = (const float*)d_in[11];
  const float* fc2b = (const float*)d_in[12];
  const float* fc3w = (const float*)d_in[13];
  const float* fc3b = (const float*)d_in[14];
  float* out = (float*)d_out;

  const int N = in_sizes[0] / 64;
  const int E = in_sizes[1] / 2;
  const int G = out_size / 10;
  const int* src = ei;
  const int* dst = ei + E;
  const int nb = (N + (1 << BSHIFT) - 1) >> BSHIFT;   // 13 for N=100K

  char* p = (char*)d_ws;
  auto alloc = [&](size_t bytes) -> void* {
    void* r = (void*)p; p += (bytes + 255) & ~(size_t)255; return r;
  };
  int*       cursor  = (int*)      alloc((size_t)N * 4);
  int*       bcnt    = (int*)      alloc(MAXB * 4);
  float*     dis     = (float*)    alloc((size_t)N * 4);
  int*       gstart  = (int*)      alloc((size_t)(G + 1) * 4);
  int*       csr     = (int*)      alloc((size_t)N * SLOT_CAP * 4);
  long long* buckets = (long long*)alloc((size_t)MAXB * BCAP * 8);
  ushort*    hlin    = (ushort*)   alloc((size_t)N * 64 * 2);
  ushort*    hA      = (ushort*)   alloc((size_t)N * 64 * 2);
  float*     zbuf    = (float*)    alloc((size_t)G * 192 * 4);
  (void)ws_size; (void)n_in;

  (void)hipMemsetAsync(cursor, 0, (size_t)N * 4, stream);
  (void)hipMemsetAsync(bcnt, 0, MAXB * 4, stream);
  (void)hipMemsetAsync(zbuf, 0, (size_t)G * 192 * 4, stream);

  int chunks = (E + FILL_CHUNK - 1) / FILL_CHUNK;
  part_k<<<chunks, 256, 0, stream>>>(src, dst, bcnt, buckets, E, nb);
  fillB_k<<<512, 256, 0, stream>>>(buckets, bcnt, cursor, csr, nb);
  dis_k<<<(N + 255) / 256, 256, 0, stream>>>(cursor, dis, N);
  bounds_k<<<(N + 255) / 256, 256, 0, stream>>>(batch, gstart, N, G);

  int gb = (N + 63) / 64;
  int ab = (N + 3) / 4;
  // layer 1
  gemm_f32_k<<<gb, 256, 0, stream>>>(x, W1, hlin, N);
  agg_k<<<ab, 256, 0, stream>>>(hlin, csr, cursor, dis, b1, hA, N);
  pool_k<<<G, 256, 0, stream>>>(hA, gstart, zbuf);
  // layer 2
  gemm_bf16_k<<<gb, 256, 0, stream>>>(hA, W2, hlin, N);
  agg_k<<<ab, 256, 0, stream>>>(hlin, csr, cursor, dis, b2, hA, N);
  pool_k<<<G, 256, 0, stream>>>(hA, gstart, zbuf);
  // layer 3
  gemm_bf16_k<<<gb, 256, 0, stream>>>(hA, W3, hlin, N);
  agg_k<<<ab, 256, 0, stream>>>(hlin, csr, cursor, dis, b3, hA, N);
  pool_k<<<G, 256, 0, stream>>>(hA, gstart, zbuf);

  mlp_k<<<G, 64, 0, stream>>>(zbuf, fc1w, fc1b, fc2w, fc2b, fc3w, fc3b, out);
}

// Round 7
// 519.404 us; speedup vs baseline: 1.0864x; 1.0864x over previous
//
#include <hip/hip_runtime.h>
#include <cmath>

typedef unsigned int uint;

// ---- bf16 helpers (manual, RNE) ----
__device__ inline float bflo(uint u) { return __uint_as_float(u << 16); }
__device__ inline float bfhi(uint u) { return __uint_as_float(u & 0xffff0000u); }
__device__ inline uint bfpack(float a, float b) {
  uint ua = __float_as_uint(a), ub = __float_as_uint(b);
  uint ra = (ua + 0x7fffu + ((ua >> 16) & 1u)) >> 16;
  uint rb = (ub + 0x7fffu + ((ub >> 16) & 1u)) >> 16;
  return ra | (rb << 16);
}
__device__ inline ushort bf1(float a) {
  uint ua = __float_as_uint(a);
  return (ushort)((ua + 0x7fffu + ((ua >> 16) & 1u)) >> 16);
}

#define SLOT_CAP 48      // max in-degree stored; Poisson(16): P(deg>=48) ~ 1e-11/node
#define FILL_CHUNK 4096
#define BSHIFT 8         // 256 nodes per bucket -> rows[256][48] = 48KB LDS
#define NPB 256
#define MAXB 512         // >= nb = ceil(100000/256) = 391
#define BCAP 5120        // per-bucket cap; mean E/391 ~ 4092, sd ~64 -> +16 sigma

// ---------------- phase A: partition edges by dst-bucket ----------------
// One pass over the edge list (nontemporal). LDS histogram -> one global
// reservation per (block,bucket) -> bucket writes are short contiguous runs.
// Bucket entry: long long, low32 = dst, high32 = src.
__global__ __launch_bounds__(256) void part_k(const int* __restrict__ src, const int* __restrict__ dst,
                                              int* __restrict__ bcnt, long long* __restrict__ buckets,
                                              int E, int nb) {
  __shared__ int lcnt[MAXB], lbase[MAXB];
  int t = threadIdx.x;
  for (int i = t; i < nb; i += 256) lcnt[i] = 0;
  __syncthreads();
  int base = blockIdx.x * FILL_CHUNK;
  int d[16];
  #pragma unroll
  for (int i = 0; i < 16; ++i) {
    int e = base + t + i * 256;
    d[i] = (e < E) ? __builtin_nontemporal_load(dst + e) : -1;
    if (d[i] >= 0) atomicAdd(&lcnt[d[i] >> BSHIFT], 1);
  }
  __syncthreads();
  for (int i = t; i < nb; i += 256) { lbase[i] = atomicAdd(&bcnt[i], lcnt[i]); lcnt[i] = 0; }
  __syncthreads();
  #pragma unroll
  for (int i = 0; i < 16; ++i) {
    if (d[i] >= 0) {
      int e = base + t + i * 256;
      int r = d[i] >> BSHIFT;
      int rank = atomicAdd(&lcnt[r], 1);
      long long s = (long long)__builtin_nontemporal_load(src + e);
      long long packed = (s << 32) | (unsigned int)d[i];
      buckets[(size_t)r * BCAP + lbase[r] + rank] = packed;
    }
  }
}

// ---------------- phase B: LDS scatter -> coalesced CSR writeout ----------------
// One block per 256-node bucket. Edges scatter into LDS rows (LDS atomics),
// then the 48KB row block streams out as full-line int4 stores. No scattered
// global writes anywhere -> no L2 writeback amplification (r6 lesson: 66MB WRITE).
__global__ __launch_bounds__(256) void fillB_k(const long long* __restrict__ buckets,
                                               const int* __restrict__ bcnt,
                                               int* __restrict__ cursor, int* __restrict__ csr,
                                               int nb, int N) {
  __shared__ int lcnt[NPB];
  __shared__ int rows[NPB][SLOT_CAP];
  int r = blockIdx.x;
  int t = threadIdx.x;
  if (t < NPB) lcnt[t] = 0;
  __syncthreads();
  int n = bcnt[r];
  const long long* bk = buckets + (size_t)r * BCAP;
  for (int i = t; i < n; i += 256) {
    long long e = __builtin_nontemporal_load(&bk[i]);
    int dl = (int)(e & (NPB - 1));       // node local id (low bits of dst)
    int s = (int)(e >> 32);
    int pos = atomicAdd(&lcnt[dl], 1);
    if (pos < SLOT_CAP) rows[dl][pos] = s;
  }
  __syncthreads();
  int base_node = r << BSHIFT;
  int nodes_here = N - base_node; if (nodes_here > NPB) nodes_here = NPB;
  if (nodes_here <= 0) return;
  int total4 = nodes_here * (SLOT_CAP / 4);
  int4* dstp = (int4*)(csr + (size_t)base_node * SLOT_CAP);
  const int4* srcp = (const int4*)&rows[0][0];
  for (int i = t; i < total4; i += 256) dstp[i] = srcp[i];
  for (int i = t; i < nodes_here; i += 256) cursor[base_node + i] = lcnt[i];
}

// dis[i] = rsqrt(true_deg + 1); cursor holds true in-degree after fill
__global__ __launch_bounds__(256) void dis_k(const int* __restrict__ cursor, float* __restrict__ dis, int n) {
  int i = blockIdx.x * 256 + threadIdx.x;
  if (i < n) dis[i] = rsqrtf((float)cursor[i] + 1.0f);
}

// graph segment boundaries (batch is sorted); gstart has G+1 entries
__global__ __launch_bounds__(256) void bounds_k(const int* __restrict__ batch, int* __restrict__ gstart,
                                                int n, int G) {
  int i = blockIdx.x * 256 + threadIdx.x;
  if (i >= n) return;
  int b = batch[i];
  int prev = (i == 0) ? -1 : batch[i - 1];
  for (int g = prev + 1; g <= b; ++g) gstart[g] = i;
  if (i == n - 1) { for (int g = b + 1; g <= G; ++g) gstart[g] = n; }
}

// ---------------- GEMM: Y[N,64](bf16) = X[N,64] @ W[64,64] ----------------

__global__ __launch_bounds__(256) void gemm_f32_k(const float* __restrict__ X, const float* __restrict__ W,
                                                  ushort* __restrict__ Y, int n) {
  __shared__ float Xs[64][64];
  int r0 = blockIdx.x * 64;
  int t = threadIdx.x;
  #pragma unroll
  for (int i = 0; i < 4; ++i) {
    int idx = t + i * 256;          // 0..1023 = 64 rows x 16 float4
    int rr = idx >> 4;
    int c4 = (idx & 15) * 4;
    int r = r0 + rr;
    float4 v = (r < n) ? ((const float4*)(X + (size_t)r * 64))[idx & 15] : make_float4(0, 0, 0, 0);
    Xs[rr][(c4 + 0 + rr) & 63] = v.x;
    Xs[rr][(c4 + 1 + rr) & 63] = v.y;
    Xs[rr][(c4 + 2 + rr) & 63] = v.z;
    Xs[rr][(c4 + 3 + rr) & 63] = v.w;
  }
  __syncthreads();
  int lane = t & 63;
  int w = t >> 6;
  float acc[16];
  #pragma unroll
  for (int c = 0; c < 16; ++c) acc[c] = 0.f;
  #pragma unroll 4
  for (int k = 0; k < 64; ++k) {
    float xv = Xs[lane][(k + lane) & 63];
    const float* wr = W + k * 64 + w * 16;   // wave-uniform -> s_load
    #pragma unroll
    for (int c = 0; c < 16; ++c) acc[c] += xv * wr[c];
  }
  int r = r0 + lane;
  if (r < n) {
    uint4* yr = (uint4*)(Y + (size_t)r * 64 + w * 16);
    yr[0] = make_uint4(bfpack(acc[0], acc[1]), bfpack(acc[2], acc[3]),
                       bfpack(acc[4], acc[5]), bfpack(acc[6], acc[7]));
    yr[1] = make_uint4(bfpack(acc[8], acc[9]), bfpack(acc[10], acc[11]),
                       bfpack(acc[12], acc[13]), bfpack(acc[14], acc[15]));
  }
}

__global__ __launch_bounds__(256) void gemm_bf16_k(const ushort* __restrict__ X, const float* __restrict__ W,
                                                   ushort* __restrict__ Y, int n) {
  __shared__ float Xs[64][64];
  int r0 = blockIdx.x * 64;
  int t = threadIdx.x;
  #pragma unroll
  for (int i = 0; i < 4; ++i) {
    int idx = t + i * 256;          // 64 rows x 16 quads of bf16
    int rr = idx >> 4;
    int c4 = (idx & 15) * 4;
    int r = r0 + rr;
    uint2 v = (r < n) ? ((const uint2*)(X + (size_t)r * 64))[idx & 15] : make_uint2(0, 0);
    Xs[rr][(c4 + 0 + rr) & 63] = bflo(v.x);
    Xs[rr][(c4 + 1 + rr) & 63] = bfhi(v.x);
    Xs[rr][(c4 + 2 + rr) & 63] = bflo(v.y);
    Xs[rr][(c4 + 3 + rr) & 63] = bfhi(v.y);
  }
  __syncthreads();
  int lane = t & 63;
  int w = t >> 6;
  float acc[16];
  #pragma unroll
  for (int c = 0; c < 16; ++c) acc[c] = 0.f;
  #pragma unroll 4
  for (int k = 0; k < 64; ++k) {
    float xv = Xs[lane][(k + lane) & 63];
    const float* wr = W + k * 64 + w * 16;
    #pragma unroll
    for (int c = 0; c < 16; ++c) acc[c] += xv * wr[c];
  }
  int r = r0 + lane;
  if (r < n) {
    uint4* yr = (uint4*)(Y + (size_t)r * 64 + w * 16);
    yr[0] = make_uint4(bfpack(acc[0], acc[1]), bfpack(acc[2], acc[3]),
                       bfpack(acc[4], acc[5]), bfpack(acc[6], acc[7]));
    yr[1] = make_uint4(bfpack(acc[8], acc[9]), bfpack(acc[10], acc[11]),
                       bfpack(acc[12], acc[13]), bfpack(acc[14], acc[15]));
  }
}

// ---------------- aggregation: one wave per node, lane = feature ----------------
// All indexing wave-uniform (node via readfirstlane) -> CSR row / degree / dis
// become s_loads; edge body ~3 VALU per edge + one 128B-coalesced row load.

__global__ __launch_bounds__(256) void agg_k(const ushort* __restrict__ Hlin,
                                             const int* __restrict__ csr,
                                             const int* __restrict__ cnt,
                                             const float* __restrict__ dis,
                                             const float* __restrict__ bias,
                                             ushort* __restrict__ Hout, int n) {
  int wv = __builtin_amdgcn_readfirstlane((int)(threadIdx.x >> 6));  // wave-uniform for LLVM
  int lane = threadIdx.x & 63;
  int node = blockIdx.x * 4 + wv;
  if (node >= n) return;
  float dn = dis[node];                        // uniform -> s_load
  float acc = bflo((uint)Hlin[(size_t)node * 64 + lane]) * (dn * dn);  // self loop
  int deg = cnt[node]; if (deg > SLOT_CAP) deg = SLOT_CAP;
  const int* row = csr + (size_t)node * SLOT_CAP;
  int e = 0;
  for (; e + 4 <= deg; e += 4) {
    int s0 = row[e + 0], s1 = row[e + 1], s2 = row[e + 2], s3 = row[e + 3];  // s_loads
    float w0 = dis[s0] * dn, w1 = dis[s1] * dn, w2 = dis[s2] * dn, w3 = dis[s3] * dn;
    float h0 = bflo((uint)Hlin[(size_t)s0 * 64 + lane]);
    float h1 = bflo((uint)Hlin[(size_t)s1 * 64 + lane]);
    float h2 = bflo((uint)Hlin[(size_t)s2 * 64 + lane]);
    float h3 = bflo((uint)Hlin[(size_t)s3 * 64 + lane]);
    acc += h0 * w0; acc += h1 * w1; acc += h2 * w2; acc += h3 * w3;
  }
  for (; e < deg; ++e) {
    int s = row[e];
    acc += bflo((uint)Hlin[(size_t)s * 64 + lane]) * (dis[s] * dn);
  }
  float v = fmaxf(acc + bias[lane], 0.f);
  Hout[(size_t)node * 64 + lane] = bf1(v);     // 128B coalesced ushort store
}

// ---------------- pooling: one block per graph, 32 rows in flight ----------------

__global__ __launch_bounds__(256) void pool_k(const ushort* __restrict__ H, const int* __restrict__ gstart,
                                              float* __restrict__ z) {
  int g = blockIdx.x;
  int t = threadIdx.x;
  int lane = t & 63, w = t >> 6;
  int slot = lane >> 3, fl = lane & 7;
  int i0 = gstart[g], i1 = gstart[g + 1];
  float s[8], m[8];
  #pragma unroll
  for (int j = 0; j < 8; ++j) { s[j] = 0.f; m[j] = 0.f; }  // max clamped at 0 (h>=0)
  for (int i = i0 + w * 8 + slot; i < i1; i += 32) {
    uint4 v = ((const uint4*)(H + (size_t)i * 64))[fl];
    float f[8] = { bflo(v.x), bfhi(v.x), bflo(v.y), bfhi(v.y),
                   bflo(v.z), bfhi(v.z), bflo(v.w), bfhi(v.w) };
    #pragma unroll
    for (int j = 0; j < 8; ++j) { s[j] += f[j]; m[j] = fmaxf(m[j], f[j]); }
  }
  #pragma unroll
  for (int msk = 8; msk <= 32; msk <<= 1) {
    #pragma unroll
    for (int j = 0; j < 8; ++j) {
      s[j] += __shfl_xor(s[j], msk, 64);
      m[j] = fmaxf(m[j], __shfl_xor(m[j], msk, 64));
    }
  }
  __shared__ float ss[4][64], sm[4][64];
  if (slot == 0) {
    #pragma unroll
    for (int j = 0; j < 8; ++j) { ss[w][fl * 8 + j] = s[j]; sm[w][fl * 8 + j] = m[j]; }
  }
  __syncthreads();
  if (t < 64) {
    float S = ss[0][t] + ss[1][t] + ss[2][t] + ss[3][t];
    float M = fmaxf(fmaxf(sm[0][t], sm[1][t]), fmaxf(sm[2][t], sm[3][t]));
    float cnt = (float)(i1 - i0);
    float mean = (cnt > 0.f) ? S / cnt : 0.f;
    z[g * 192 + t]       += mean;
    z[g * 192 + 64 + t]  += M;
    z[g * 192 + 128 + t] += S;
  }
}

// ---------------- MLP head + log_softmax ----------------
__global__ __launch_bounds__(64) void mlp_k(const float* __restrict__ z,
                                            const float* __restrict__ fc1w, const float* __restrict__ fc1b,
                                            const float* __restrict__ fc2w, const float* __restrict__ fc2b,
                                            const float* __restrict__ fc3w, const float* __restrict__ fc3b,
                                            float* __restrict__ out) {
  int g = blockIdx.x; int t = threadIdx.x;
  __shared__ float zr[192], a1[64], a2[32], a3[10];
  for (int i = t; i < 192; i += 64) zr[i] = z[g * 192 + i];
  __syncthreads();
  float acc = fc1b[t];
  for (int k = 0; k < 192; ++k) acc += zr[k] * fc1w[k * 64 + t];
  a1[t] = fmaxf(acc, 0.f);
  __syncthreads();
  if (t < 32) {
    float a = fc2b[t];
    #pragma unroll
    for (int k = 0; k < 64; ++k) a += a1[k] * fc2w[k * 32 + t];
    a2[t] = fmaxf(a, 0.f);
  }
  __syncthreads();
  if (t < 10) {
    float a = fc3b[t];
    #pragma unroll
    for (int k = 0; k < 32; ++k) a += a2[k] * fc3w[k * 10 + t];
    a3[t] = a;
  }
  __syncthreads();
  if (t == 0) {
    float mx = a3[0];
    for (int i = 1; i < 10; ++i) mx = fmaxf(mx, a3[i]);
    float sum = 0.f;
    for (int i = 0; i < 10; ++i) sum += expf(a3[i] - mx);
    float lse = mx + logf(sum);
    for (int i = 0; i < 10; ++i) out[g * 10 + i] = a3[i] - lse;
  }
}

extern "C" void kernel_launch(void* const* d_in, const int* in_sizes, int n_in,
                              void* d_out, int out_size, void* d_ws, size_t ws_size,
                              hipStream_t stream) {
  const float* x    = (const float*)d_in[0];
  const int*   ei   = (const int*)  d_in[1];
  const int*   batch= (const int*)  d_in[2];
  const float* W1   = (const float*)d_in[3];
  const float* b1   = (const float*)d_in[4];
  const float* W2   = (const float*)d_in[5];
  const float* b2   = (const float*)d_in[6];
  const float* W3   = (const float*)d_in[7];
  const float* b3   = (const float*)d_in[8];
  const float* fc1w = (const float*)d_in[9];
  const float* fc1b = (const float*)d_in[10];
  const float* fc2w = (const float*)d_in[11];
  const float* fc2b = (const float*)d_in[12];
  const float* fc3w = (const float*)d_in[13];
  const float* fc3b = (const float*)d_in[14];
  float* out = (float*)d_out;

  const int N = in_sizes[0] / 64;
  const int E = in_sizes[1] / 2;
  const int G = out_size / 10;
  const int* src = ei;
  const int* dst = ei + E;
  const int nb = (N + NPB - 1) >> BSHIFT;   // 391 for N=100K

  char* p = (char*)d_ws;
  auto alloc = [&](size_t bytes) -> void* {
    void* r = (void*)p; p += (bytes + 255) & ~(size_t)255; return r;
  };
  int*       cursor  = (int*)      alloc((size_t)N * 4);
  int*       bcnt    = (int*)      alloc(MAXB * 4);
  float*     dis     = (float*)    alloc((size_t)N * 4);
  int*       gstart  = (int*)      alloc((size_t)(G + 1) * 4);
  int*       csr     = (int*)      alloc((size_t)(nb * NPB) * SLOT_CAP * 4);
  long long* buckets = (long long*)alloc((size_t)nb * BCAP * 8);
  ushort*    hlin    = (ushort*)   alloc((size_t)N * 64 * 2);
  ushort*    hA      = (ushort*)   alloc((size_t)N * 64 * 2);
  float*     zbuf    = (float*)    alloc((size_t)G * 192 * 4);
  (void)ws_size; (void)n_in;

  (void)hipMemsetAsync(bcnt, 0, MAXB * 4, stream);
  (void)hipMemsetAsync(zbuf, 0, (size_t)G * 192 * 4, stream);

  int chunks = (E + FILL_CHUNK - 1) / FILL_CHUNK;
  part_k<<<chunks, 256, 0, stream>>>(src, dst, bcnt, buckets, E, nb);
  fillB_k<<<nb, 256, 0, stream>>>(buckets, bcnt, cursor, csr, nb, N);
  dis_k<<<(N + 255) / 256, 256, 0, stream>>>(cursor, dis, N);
  bounds_k<<<(N + 255) / 256, 256, 0, stream>>>(batch, gstart, N, G);

  int gb = (N + 63) / 64;
  int ab = (N + 3) / 4;
  // layer 1
  gemm_f32_k<<<gb, 256, 0, stream>>>(x, W1, hlin, N);
  agg_k<<<ab, 256, 0, stream>>>(hlin, csr, cursor, dis, b1, hA, N);
  pool_k<<<G, 256, 0, stream>>>(hA, gstart, zbuf);
  // layer 2
  gemm_bf16_k<<<gb, 256, 0, stream>>>(hA, W2, hlin, N);
  agg_k<<<ab, 256, 0, stream>>>(hlin, csr, cursor, dis, b2, hA, N);
  pool_k<<<G, 256, 0, stream>>>(hA, gstart, zbuf);
  // layer 3
  gemm_bf16_k<<<gb, 256, 0, stream>>>(hA, W3, hlin, N);
  agg_k<<<ab, 256, 0, stream>>>(hlin, csr, cursor, dis, b3, hA, N);
  pool_k<<<G, 256, 0, stream>>>(hA, gstart, zbuf);

  mlp_k<<<G, 64, 0, stream>>>(zbuf, fc1w, fc1b, fc2w, fc2b, fc3w, fc3b, out);
}

// Round 8
// 397.538 us; speedup vs baseline: 1.4195x; 1.3066x over previous
//
#include <hip/hip_runtime.h>
#include <cmath>

typedef unsigned int uint;
typedef __attribute__((ext_vector_type(8))) short short8;   // 8 bf16 = 4 VGPRs
typedef __attribute__((ext_vector_type(4))) float f32x4;

// ---- bf16 helpers (manual, RNE) ----
__device__ inline float bflo(uint u) { return __uint_as_float(u << 16); }
__device__ inline float bfhi(uint u) { return __uint_as_float(u & 0xffff0000u); }
__device__ inline ushort bf1(float a) {
  uint ua = __float_as_uint(a);
  return (ushort)((ua + 0x7fffu + ((ua >> 16) & 1u)) >> 16);
}
__device__ inline uint bfpack(float a, float b) {
  uint ua = __float_as_uint(a), ub = __float_as_uint(b);
  uint ra = (ua + 0x7fffu + ((ua >> 16) & 1u)) >> 16;
  uint rb = (ub + 0x7fffu + ((ub >> 16) & 1u)) >> 16;
  return ra | (rb << 16);
}

#define SLOT_CAP 48      // max in-degree stored; Poisson(16): P(deg>=48) ~ 1e-11/node
#define FILL_CHUNK 4096
#define BSHIFT 8         // 256 nodes per bucket -> rows[256][48] = 48KB LDS
#define NPB 256
#define MAXB 512         // >= nb = ceil(100000/256) = 391
#define BCAP 5120        // per-bucket cap; mean E/391 ~ 4092, sd ~64 -> +16 sigma

// ---------------- phase A: partition edges by dst-bucket ----------------
__global__ __launch_bounds__(256) void part_k(const int* __restrict__ src, const int* __restrict__ dst,
                                              int* __restrict__ bcnt, long long* __restrict__ buckets,
                                              int E, int nb) {
  __shared__ int lcnt[MAXB], lbase[MAXB];
  int t = threadIdx.x;
  for (int i = t; i < nb; i += 256) lcnt[i] = 0;
  __syncthreads();
  int base = blockIdx.x * FILL_CHUNK;
  int d[16];
  #pragma unroll
  for (int i = 0; i < 16; ++i) {
    int e = base + t + i * 256;
    d[i] = (e < E) ? __builtin_nontemporal_load(dst + e) : -1;
    if (d[i] >= 0) atomicAdd(&lcnt[d[i] >> BSHIFT], 1);
  }
  __syncthreads();
  for (int i = t; i < nb; i += 256) { lbase[i] = atomicAdd(&bcnt[i], lcnt[i]); lcnt[i] = 0; }
  __syncthreads();
  #pragma unroll
  for (int i = 0; i < 16; ++i) {
    if (d[i] >= 0) {
      int e = base + t + i * 256;
      int r = d[i] >> BSHIFT;
      int rank = atomicAdd(&lcnt[r], 1);
      long long s = (long long)__builtin_nontemporal_load(src + e);
      long long packed = (s << 32) | (unsigned int)d[i];
      buckets[(size_t)r * BCAP + lbase[r] + rank] = packed;
    }
  }
}

// ---------------- phase B: LDS scatter -> coalesced CSR writeout ----------------
__global__ __launch_bounds__(256) void fillB_k(const long long* __restrict__ buckets,
                                               const int* __restrict__ bcnt,
                                               int* __restrict__ cursor, int* __restrict__ csr,
                                               int nb, int N) {
  __shared__ int lcnt[NPB];
  __shared__ int rows[NPB][SLOT_CAP];
  int r = blockIdx.x;
  int t = threadIdx.x;
  if (t < NPB) lcnt[t] = 0;
  __syncthreads();
  int n = bcnt[r];
  const long long* bk = buckets + (size_t)r * BCAP;
  for (int i = t; i < n; i += 256) {
    long long e = __builtin_nontemporal_load(&bk[i]);
    int dl = (int)(e & (NPB - 1));
    int s = (int)(e >> 32);
    int pos = atomicAdd(&lcnt[dl], 1);
    if (pos < SLOT_CAP) rows[dl][pos] = s;
  }
  __syncthreads();
  int base_node = r << BSHIFT;
  int nodes_here = N - base_node; if (nodes_here > NPB) nodes_here = NPB;
  if (nodes_here <= 0) return;
  int total4 = nodes_here * (SLOT_CAP / 4);
  int4* dstp = (int4*)(csr + (size_t)base_node * SLOT_CAP);
  const int4* srcp = (const int4*)&rows[0][0];
  for (int i = t; i < total4; i += 256) dstp[i] = srcp[i];
  for (int i = t; i < nodes_here; i += 256) cursor[base_node + i] = lcnt[i];
}

// dis[i] = rsqrt(true_deg + 1)
__global__ __launch_bounds__(256) void dis_k(const int* __restrict__ cursor, float* __restrict__ dis, int n) {
  int i = blockIdx.x * 256 + threadIdx.x;
  if (i < n) dis[i] = rsqrtf((float)cursor[i] + 1.0f);
}

// graph segment boundaries (batch sorted)
__global__ __launch_bounds__(256) void bounds_k(const int* __restrict__ batch, int* __restrict__ gstart,
                                                int n, int G) {
  int i = blockIdx.x * 256 + threadIdx.x;
  if (i >= n) return;
  int b = batch[i];
  int prev = (i == 0) ? -1 : batch[i - 1];
  for (int g = prev + 1; g <= b; ++g) gstart[g] = i;
  if (i == n - 1) { for (int g = b + 1; g <= G; ++g) gstart[g] = n; }
}

// ---------------- prep: X f32 -> bf16 ; W f32 -> WT bf16 (transposed) ----------------
__global__ __launch_bounds__(256) void xcast_k(const float* __restrict__ X, ushort* __restrict__ Y, int total4) {
  int i = blockIdx.x * 256 + threadIdx.x;   // one float4 -> one uint2 (4 bf16)
  if (i >= total4) return;
  float4 v = ((const float4*)X)[i];
  ((uint2*)Y)[i] = make_uint2(bfpack(v.x, v.y), bfpack(v.z, v.w));
}

__global__ __launch_bounds__(256) void wt_k(const float* __restrict__ W, ushort* __restrict__ WT) {
  int i = blockIdx.x * 256 + threadIdx.x;   // 4096 elements
  int c = i >> 6, k = i & 63;
  WT[i] = bf1(W[k * 64 + c]);               // WT[c][k] = W[k][c]
}

// ---------------- GEMM via MFMA: Y[N,64](bf16) = X[N,64](bf16) @ W ----------------
// One wave = 16 rows x 64 cols, K=64: 4 col-tiles x 2 K-chunks = 8 MFMAs.
// A-frag: A[m=lane&15][k=quad*8+j] -> 16B contiguous from row-major X.
// B-frag: B[k][n=ct*16+(lane&15)]  -> 16B contiguous from WT[c][k].
// C/D:    col=lane&15, row=quad*4+reg.
__global__ __launch_bounds__(256) void gemm_mfma_k(const ushort* __restrict__ X,
                                                   const ushort* __restrict__ WT,
                                                   ushort* __restrict__ Y, int n) {
  int t = threadIdx.x;
  int wv = t >> 6, lane = t & 63;
  int m = lane & 15, quad = lane >> 4;
  int row = blockIdx.x * 64 + wv * 16 + m;
  int rclamp = (row < n) ? row : 0;
  const short8* arow = (const short8*)(X + (size_t)rclamp * 64);
  short8 a0 = arow[quad];        // k = quad*8 + 0..7
  short8 a1 = arow[quad + 4];    // k = 32 + quad*8 + 0..7
  f32x4 acc[4];
  #pragma unroll
  for (int ct = 0; ct < 4; ++ct) {
    const short8* wrow = (const short8*)(WT + (size_t)(ct * 16 + m) * 64);
    short8 b0 = wrow[quad];
    short8 b1 = wrow[quad + 4];
    f32x4 a = {0.f, 0.f, 0.f, 0.f};
    a = __builtin_amdgcn_mfma_f32_16x16x32_bf16(a0, b0, a, 0, 0, 0);
    a = __builtin_amdgcn_mfma_f32_16x16x32_bf16(a1, b1, a, 0, 0, 0);
    acc[ct] = a;
  }
  int orow = blockIdx.x * 64 + wv * 16 + quad * 4;
  #pragma unroll
  for (int reg = 0; reg < 4; ++reg) {
    int r = orow + reg;
    if (r < n) {
      #pragma unroll
      for (int ct = 0; ct < 4; ++ct)
        Y[(size_t)r * 64 + ct * 16 + m] = bf1(acc[ct][reg]);
    }
  }
}

// ---------------- aggregation: one wave per node, lane = feature ----------------
__global__ __launch_bounds__(256) void agg_k(const ushort* __restrict__ Hlin,
                                             const int* __restrict__ csr,
                                             const int* __restrict__ cnt,
                                             const float* __restrict__ dis,
                                             const float* __restrict__ bias,
                                             ushort* __restrict__ Hout, int n) {
  int wv = __builtin_amdgcn_readfirstlane((int)(threadIdx.x >> 6));
  int lane = threadIdx.x & 63;
  int node = blockIdx.x * 4 + wv;
  if (node >= n) return;
  float dn = dis[node];
  float acc = bflo((uint)Hlin[(size_t)node * 64 + lane]) * (dn * dn);  // self loop
  int deg = cnt[node]; if (deg > SLOT_CAP) deg = SLOT_CAP;
  const int* row = csr + (size_t)node * SLOT_CAP;
  int e = 0;
  for (; e + 4 <= deg; e += 4) {
    int s0 = row[e + 0], s1 = row[e + 1], s2 = row[e + 2], s3 = row[e + 3];
    float w0 = dis[s0] * dn, w1 = dis[s1] * dn, w2 = dis[s2] * dn, w3 = dis[s3] * dn;
    float h0 = bflo((uint)Hlin[(size_t)s0 * 64 + lane]);
    float h1 = bflo((uint)Hlin[(size_t)s1 * 64 + lane]);
    float h2 = bflo((uint)Hlin[(size_t)s2 * 64 + lane]);
    float h3 = bflo((uint)Hlin[(size_t)s3 * 64 + lane]);
    acc += h0 * w0; acc += h1 * w1; acc += h2 * w2; acc += h3 * w3;
  }
  for (; e < deg; ++e) {
    int s = row[e];
    acc += bflo((uint)Hlin[(size_t)s * 64 + lane]) * (dis[s] * dn);
  }
  float v = fmaxf(acc + bias[lane], 0.f);
  Hout[(size_t)node * 64 + lane] = bf1(v);
}

// ---------------- pooling: one block per graph, 32 rows in flight ----------------
__global__ __launch_bounds__(256) void pool_k(const ushort* __restrict__ H, const int* __restrict__ gstart,
                                              float* __restrict__ z) {
  int g = blockIdx.x;
  int t = threadIdx.x;
  int lane = t & 63, w = t >> 6;
  int slot = lane >> 3, fl = lane & 7;
  int i0 = gstart[g], i1 = gstart[g + 1];
  float s[8], m[8];
  #pragma unroll
  for (int j = 0; j < 8; ++j) { s[j] = 0.f; m[j] = 0.f; }  // max clamped at 0 (h>=0)
  for (int i = i0 + w * 8 + slot; i < i1; i += 32) {
    uint4 v = ((const uint4*)(H + (size_t)i * 64))[fl];
    float f[8] = { bflo(v.x), bfhi(v.x), bflo(v.y), bfhi(v.y),
                   bflo(v.z), bfhi(v.z), bflo(v.w), bfhi(v.w) };
    #pragma unroll
    for (int j = 0; j < 8; ++j) { s[j] += f[j]; m[j] = fmaxf(m[j], f[j]); }
  }
  #pragma unroll
  for (int msk = 8; msk <= 32; msk <<= 1) {
    #pragma unroll
    for (int j = 0; j < 8; ++j) {
      s[j] += __shfl_xor(s[j], msk, 64);
      m[j] = fmaxf(m[j], __shfl_xor(m[j], msk, 64));
    }
  }
  __shared__ float ss[4][64], sm[4][64];
  if (slot == 0) {
    #pragma unroll
    for (int j = 0; j < 8; ++j) { ss[w][fl * 8 + j] = s[j]; sm[w][fl * 8 + j] = m[j]; }
  }
  __syncthreads();
  if (t < 64) {
    float S = ss[0][t] + ss[1][t] + ss[2][t] + ss[3][t];
    float M = fmaxf(fmaxf(sm[0][t], sm[1][t]), fmaxf(sm[2][t], sm[3][t]));
    float cnt = (float)(i1 - i0);
    float mean = (cnt > 0.f) ? S / cnt : 0.f;
    z[g * 192 + t]       += mean;
    z[g * 192 + 64 + t]  += M;
    z[g * 192 + 128 + t] += S;
  }
}

// ---------------- MLP head + log_softmax ----------------
__global__ __launch_bounds__(64) void mlp_k(const float* __restrict__ z,
                                            const float* __restrict__ fc1w, const float* __restrict__ fc1b,
                                            const float* __restrict__ fc2w, const float* __restrict__ fc2b,
                                            const float* __restrict__ fc3w, const float* __restrict__ fc3b,
                                            float* __restrict__ out) {
  int g = blockIdx.x; int t = threadIdx.x;
  __shared__ float zr[192], a1[64], a2[32], a3[10];
  for (int i = t; i < 192; i += 64) zr[i] = z[g * 192 + i];
  __syncthreads();
  float acc = fc1b[t];
  for (int k = 0; k < 192; ++k) acc += zr[k] * fc1w[k * 64 + t];
  a1[t] = fmaxf(acc, 0.f);
  __syncthreads();
  if (t < 32) {
    float a = fc2b[t];
    #pragma unroll
    for (int k = 0; k < 64; ++k) a += a1[k] * fc2w[k * 32 + t];
    a2[t] = fmaxf(a, 0.f);
  }
  __syncthreads();
  if (t < 10) {
    float a = fc3b[t];
    #pragma unroll
    for (int k = 0; k < 32; ++k) a += a2[k] * fc3w[k * 10 + t];
    a3[t] = a;
  }
  __syncthreads();
  if (t == 0) {
    float mx = a3[0];
    for (int i = 1; i < 10; ++i) mx = fmaxf(mx, a3[i]);
    float sum = 0.f;
    for (int i = 0; i < 10; ++i) sum += expf(a3[i] - mx);
    float lse = mx + logf(sum);
    for (int i = 0; i < 10; ++i) out[g * 10 + i] = a3[i] - lse;
  }
}

extern "C" void kernel_launch(void* const* d_in, const int* in_sizes, int n_in,
                              void* d_out, int out_size, void* d_ws, size_t ws_size,
                              hipStream_t stream) {
  const float* x    = (const float*)d_in[0];
  const int*   ei   = (const int*)  d_in[1];
  const int*   batch= (const int*)  d_in[2];
  const float* W1   = (const float*)d_in[3];
  const float* b1   = (const float*)d_in[4];
  const float* W2   = (const float*)d_in[5];
  const float* b2   = (const float*)d_in[6];
  const float* W3   = (const float*)d_in[7];
  const float* b3   = (const float*)d_in[8];
  const float* fc1w = (const float*)d_in[9];
  const float* fc1b = (const float*)d_in[10];
  const float* fc2w = (const float*)d_in[11];
  const float* fc2b = (const float*)d_in[12];
  const float* fc3w = (const float*)d_in[13];
  const float* fc3b = (const float*)d_in[14];
  float* out = (float*)d_out;

  const int N = in_sizes[0] / 64;
  const int E = in_sizes[1] / 2;
  const int G = out_size / 10;
  const int* src = ei;
  const int* dst = ei + E;
  const int nb = (N + NPB - 1) >> BSHIFT;   // 391 for N=100K

  char* p = (char*)d_ws;
  auto alloc = [&](size_t bytes) -> void* {
    void* r = (void*)p; p += (bytes + 255) & ~(size_t)255; return r;
  };
  int*       cursor  = (int*)      alloc((size_t)N * 4);
  int*       bcnt    = (int*)      alloc(MAXB * 4);
  float*     dis     = (float*)    alloc((size_t)N * 4);
  int*       gstart  = (int*)      alloc((size_t)(G + 1) * 4);
  int*       csr     = (int*)      alloc((size_t)(nb * NPB) * SLOT_CAP * 4);
  long long* buckets = (long long*)alloc((size_t)nb * BCAP * 8);
  ushort*    xbf     = (ushort*)   alloc((size_t)N * 64 * 2);
  ushort*    wt1     = (ushort*)   alloc(4096 * 2);
  ushort*    wt2     = (ushort*)   alloc(4096 * 2);
  ushort*    wt3     = (ushort*)   alloc(4096 * 2);
  ushort*    hlin    = (ushort*)   alloc((size_t)N * 64 * 2);
  ushort*    hA      = (ushort*)   alloc((size_t)N * 64 * 2);
  float*     zbuf    = (float*)    alloc((size_t)G * 192 * 4);
  (void)ws_size; (void)n_in;

  (void)hipMemsetAsync(bcnt, 0, MAXB * 4, stream);
  (void)hipMemsetAsync(zbuf, 0, (size_t)G * 192 * 4, stream);

  int chunks = (E + FILL_CHUNK - 1) / FILL_CHUNK;
  part_k<<<chunks, 256, 0, stream>>>(src, dst, bcnt, buckets, E, nb);
  fillB_k<<<nb, 256, 0, stream>>>(buckets, bcnt, cursor, csr, nb, N);
  dis_k<<<(N + 255) / 256, 256, 0, stream>>>(cursor, dis, N);
  bounds_k<<<(N + 255) / 256, 256, 0, stream>>>(batch, gstart, N, G);
  xcast_k<<<(N * 16 + 255) / 256, 256, 0, stream>>>(x, xbf, N * 16);
  wt_k<<<16, 256, 0, stream>>>(W1, wt1);
  wt_k<<<16, 256, 0, stream>>>(W2, wt2);
  wt_k<<<16, 256, 0, stream>>>(W3, wt3);

  int gb = (N + 63) / 64;
  int ab = (N + 3) / 4;
  // layer 1
  gemm_mfma_k<<<gb, 256, 0, stream>>>(xbf, wt1, hlin, N);
  agg_k<<<ab, 256, 0, stream>>>(hlin, csr, cursor, dis, b1, hA, N);
  pool_k<<<G, 256, 0, stream>>>(hA, gstart, zbuf);
  // layer 2
  gemm_mfma_k<<<gb, 256, 0, stream>>>(hA, wt2, hlin, N);
  agg_k<<<ab, 256, 0, stream>>>(hlin, csr, cursor, dis, b2, hA, N);
  pool_k<<<G, 256, 0, stream>>>(hA, gstart, zbuf);
  // layer 3
  gemm_mfma_k<<<gb, 256, 0, stream>>>(hA, wt3, hlin, N);
  agg_k<<<ab, 256, 0, stream>>>(hlin, csr, cursor, dis, b3, hA, N);
  pool_k<<<G, 256, 0, stream>>>(hA, gstart, zbuf);

  mlp_k<<<G, 64, 0, stream>>>(zbuf, fc1w, fc1b, fc2w, fc2b, fc3w, fc3b, out);
}